// Round 2
// baseline (219.677 us; speedup 1.0000x reference)
//
#include <hip/hip_runtime.h>
#include <hip/hip_bf16.h>

// Sizes (compile-time): S=128, B=64, N=64, K=16, P=48, M=32
// w (LSTM hidden outputs): [S,B,16]
// Outputs: A [S,B,64,64] (C=4096), Bo [S,B,64,32] (C=2048), Cc [S,B,48,64] (C=3072)

#define SB 8192      // S*B
#define NN 64        // N (=4*K, same value)

// ---------------------------------------------------------------------------
// Kernel 1: xg[row][g] = dot(x[row][:], W_ih[g][:]) + b_ih[g] + b_hh[g]
// row in [0,8192), g in [0,64). Block = 256 threads = 4 rows x 64 g.
// ---------------------------------------------------------------------------
__global__ __launch_bounds__(256) void xgate_kernel(
    const float* __restrict__ x,    // [8192][64]
    const float* __restrict__ Wih,  // [64][64]
    const float* __restrict__ bih,  // [64]
    const float* __restrict__ bhh,  // [64]
    float* __restrict__ xg)         // [8192][64]
{
    __shared__ float xs[4][64];
    const int tid = threadIdx.x;
    const int rl  = tid >> 6;           // row within block (0..3)
    const int g   = tid & 63;
    const size_t rowBase = (size_t)blockIdx.x * 4;

    // cooperative load of the 4 input rows (contiguous 256 floats)
    xs[rl][g] = x[rowBase * 64 + tid];
    __syncthreads();

    const float* xr = xs[rl];           // all 64 lanes of a wave read same row -> LDS broadcast
    float acc = bih[g] + bhh[g];
#pragma unroll
    for (int n = 0; n < 64; n += 4) {
        float4 wv = *reinterpret_cast<const float4*>(&Wih[g * 64 + n]);
        acc = fmaf(xr[n + 0], wv.x, acc);
        acc = fmaf(xr[n + 1], wv.y, acc);
        acc = fmaf(xr[n + 2], wv.z, acc);
        acc = fmaf(xr[n + 3], wv.w, acc);
    }
    xg[(rowBase + rl) * 64 + g] = acc;
}

// ---------------------------------------------------------------------------
// Kernel 2: sequential LSTM scan. 1024 threads total: lane = b*16 + t.
// Each thread owns hidden unit t of batch b; h broadcast via width-16 shfl.
// PyTorch gate order: i, f, g, o.
// ---------------------------------------------------------------------------
__global__ __launch_bounds__(64) void lstm_scan_kernel(
    const float* __restrict__ xg,   // [S][B][64]
    const float* __restrict__ Whh,  // [64][16]
    float* __restrict__ w)          // [S][B][16]
{
    const int gtid = blockIdx.x * 64 + threadIdx.x;  // 0..1023
    const int t = gtid & 15;        // hidden unit
    const int b = gtid >> 4;        // batch 0..63

    // preload recurrent weights for this unit's 4 gates
    float wi[16], wf[16], wg[16], wo[16];
#pragma unroll
    for (int k = 0; k < 16; ++k) {
        wi[k] = Whh[(0 * 16 + t) * 16 + k];
        wf[k] = Whh[(1 * 16 + t) * 16 + k];
        wg[k] = Whh[(2 * 16 + t) * 16 + k];
        wo[k] = Whh[(3 * 16 + t) * 16 + k];
    }

    float h = 0.f, c = 0.f;
    for (int s = 0; s < 128; ++s) {
        const float* xr = xg + ((size_t)s * 64 + b) * 64;
        float ai = xr[0 * 16 + t];
        float af = xr[1 * 16 + t];
        float ag = xr[2 * 16 + t];
        float ao = xr[3 * 16 + t];
#pragma unroll
        for (int k = 0; k < 16; ++k) {
            float hk = __shfl(h, k, 16);   // broadcast h[b][k] within 16-lane group
            ai = fmaf(hk, wi[k], ai);
            af = fmaf(hk, wf[k], af);
            ag = fmaf(hk, wg[k], ag);
            ao = fmaf(hk, wo[k], ao);
        }
        float ig = 1.f / (1.f + __expf(-ai));
        float fg = 1.f / (1.f + __expf(-af));
        float og = 1.f / (1.f + __expf(-ao));
        float gt = tanhf(ag);
        c = fg * c + ig * gt;
        h = og * tanhf(c);
        w[((size_t)s * 64 + b) * 16 + t] = h;
    }
}

// ---------------------------------------------------------------------------
// Kernel 3: out[row][i] = sum_k w[row][k] * Mats[k][i]  (tall-skinny GEMM, K=16)
// Block: 256 threads x float4 -> 1024 columns, 64 rows. Matrix slice in
// registers (16 float4), w tile in LDS (broadcast reads), streaming f4 stores.
// ---------------------------------------------------------------------------
template <int C>
__global__ __launch_bounds__(256) void wsum_kernel(
    const float* __restrict__ w,     // [8192][16]
    const float* __restrict__ Mats,  // [16][C]
    float* __restrict__ out)         // [8192][C]
{
    constexpr int COLT = C / 1024;   // column tiles
    __shared__ float ws[64 * 16];

    const int tid = threadIdx.x;
    const int colTile  = blockIdx.x % COLT;
    const int rowStart = (blockIdx.x / COLT) * 64;
    const int i4 = colTile * 1024 + tid * 4;

    // stage 64 rows of w (1024 contiguous floats)
    *reinterpret_cast<float4*>(&ws[tid * 4]) =
        *reinterpret_cast<const float4*>(&w[(size_t)rowStart * 16 + tid * 4]);

    // load this thread's 4-column slice of all 16 matrices into registers
    float4 m[16];
#pragma unroll
    for (int k = 0; k < 16; ++k)
        m[k] = *reinterpret_cast<const float4*>(&Mats[(size_t)k * C + i4]);

    __syncthreads();

    for (int r = 0; r < 64; ++r) {
        const float* wr = &ws[r * 16];
        float4 acc = make_float4(0.f, 0.f, 0.f, 0.f);
#pragma unroll
        for (int k = 0; k < 16; ++k) {
            float wk = wr[k];          // LDS broadcast (same addr all lanes)
            acc.x = fmaf(wk, m[k].x, acc.x);
            acc.y = fmaf(wk, m[k].y, acc.y);
            acc.z = fmaf(wk, m[k].z, acc.z);
            acc.w = fmaf(wk, m[k].w, acc.w);
        }
        *reinterpret_cast<float4*>(&out[(size_t)(rowStart + r) * C + i4]) = acc;
    }
}

// ---------------------------------------------------------------------------
extern "C" void kernel_launch(void* const* d_in, const int* in_sizes, int n_in,
                              void* d_out, int out_size, void* d_ws, size_t ws_size,
                              hipStream_t stream) {
    const float* state = (const float*)d_in[0];  // [128,64,64]
    const float* W_ih  = (const float*)d_in[1];  // [64,64]
    const float* W_hh  = (const float*)d_in[2];  // [64,16]
    const float* b_ih  = (const float*)d_in[3];  // [64]
    const float* b_hh  = (const float*)d_in[4];  // [64]
    const float* As    = (const float*)d_in[5];  // [16,64,64]
    const float* Bs    = (const float*)d_in[6];  // [16,64,32]
    const float* Cs    = (const float*)d_in[7];  // [16,48,64]
    float* out = (float*)d_out;

    float* xg = (float*)d_ws;            // 8192*64 floats = 2 MiB
    float* w  = xg + (size_t)SB * 64;    // 8192*16 floats = 512 KiB

    xgate_kernel<<<SB / 4, 256, 0, stream>>>(state, W_ih, b_ih, b_hh, xg);
    lstm_scan_kernel<<<16, 64, 0, stream>>>(xg, W_hh, w);

    float* outA = out;                                   // [8192][4096]
    float* outB = out + (size_t)SB * 4096;               // [8192][2048]
    float* outC = out + (size_t)SB * 4096 + (size_t)SB * 2048;  // [8192][3072]

    wsum_kernel<4096><<<(4096 / 1024) * (SB / 64), 256, 0, stream>>>(w, As, outA);
    wsum_kernel<2048><<<(2048 / 1024) * (SB / 64), 256, 0, stream>>>(w, Bs, outB);
    wsum_kernel<3072><<<(3072 / 1024) * (SB / 64), 256, 0, stream>>>(w, Cs, outC);
}

// Round 4
// 128.328 us; speedup vs baseline: 1.7118x; 1.7118x over previous
//
#include <hip/hip_runtime.h>
#include <hip/hip_bf16.h>

// Sizes: S=128, B=64, N=64, K=16, P=48, M=32
// Outputs: A [S,B,64,64] (C=4096), Bo [S,B,64,32] (C=2048), Cc [S,B,48,64] (C=3072)
#define SB 8192   // S*B

typedef float f4 __attribute__((ext_vector_type(4)));  // clang-native vec4

__device__ __forceinline__ float fsig(float x) {
    return __builtin_amdgcn_rcpf(1.f + __expf(-x));
}
__device__ __forceinline__ float ftanh(float x) {
    // tanh(x) = 1 - 2/(exp(2x)+1); correct limits at +-inf via rcp(inf)=0
    return fmaf(-2.f, __builtin_amdgcn_rcpf(1.f + __expf(2.f * x)), 1.f);
}

// ---------------------------------------------------------------------------
// Kernel 1: xg[row][t*4+q] = dot(x[row], W_ih[q*16+t]) + b_ih[g] + b_hh[g]
// Gate-interleaved layout so the scan loads one float4 per step.
// ---------------------------------------------------------------------------
__global__ __launch_bounds__(256) void xgate_kernel(
    const float* __restrict__ x,    // [8192][64]
    const float* __restrict__ Wih,  // [64][64]
    const float* __restrict__ bih,  // [64]
    const float* __restrict__ bhh,  // [64]
    float* __restrict__ xg)         // [8192][16][4] gate-interleaved
{
    __shared__ float xs[4][64];
    const int tid = threadIdx.x;
    const int rl  = tid >> 6;
    const int g   = tid & 63;           // weight row: g = q*16 + t
    const size_t rowBase = (size_t)blockIdx.x * 4;

    xs[rl][g] = x[rowBase * 64 + tid];
    __syncthreads();

    const float* xr = xs[rl];
    float acc = bih[g] + bhh[g];
#pragma unroll
    for (int n = 0; n < 64; n += 4) {
        f4 wv = *reinterpret_cast<const f4*>(&Wih[g * 64 + n]);
        acc = fmaf(xr[n + 0], wv.x, acc);
        acc = fmaf(xr[n + 1], wv.y, acc);
        acc = fmaf(xr[n + 2], wv.z, acc);
        acc = fmaf(xr[n + 3], wv.w, acc);
    }
    // remap: unit t = g&15, gate q = g>>4  ->  slot t*4+q
    xg[(rowBase + rl) * 64 + (g & 15) * 4 + (g >> 4)] = acc;
}

// ---------------------------------------------------------------------------
// Kernel 2: sequential LSTM scan. 1024 threads: thread owns (batch b, unit t).
// float4 gate load per step, software-pipelined one step ahead; h broadcast
// via width-16 shfl; fast sigmoid/tanh on v_exp/v_rcp.
// ---------------------------------------------------------------------------
__global__ __launch_bounds__(64) void lstm_scan_kernel(
    const float* __restrict__ xg,   // [S][B][16][4]
    const float* __restrict__ Whh,  // [64][16]
    float* __restrict__ w)          // [S][B][16]
{
    const int gtid = blockIdx.x * 64 + threadIdx.x;
    const int t = gtid & 15;
    const int b = gtid >> 4;

    float wi[16], wf[16], wg[16], wo[16];
#pragma unroll
    for (int k = 0; k < 16; ++k) {
        wi[k] = Whh[(0 * 16 + t) * 16 + k];
        wf[k] = Whh[(1 * 16 + t) * 16 + k];
        wg[k] = Whh[(2 * 16 + t) * 16 + k];
        wo[k] = Whh[(3 * 16 + t) * 16 + k];
    }

    // f4 view: element (s,b,t) at f4-index (s*64+b)*16 + t; s-stride = 1024
    const f4* xp = reinterpret_cast<const f4*>(xg) + b * 16 + t;
    f4 xv = xp[0];
    float h = 0.f, c = 0.f;
    for (int s = 0; s < 128; ++s) {
        f4 nx = (s < 127) ? xp[(size_t)(s + 1) * 1024] : (f4)0.f;
        float ai = xv.x, af = xv.y, ag = xv.z, ao = xv.w;
#pragma unroll
        for (int k = 0; k < 16; ++k) {
            float hk = __shfl(h, k, 16);
            ai = fmaf(hk, wi[k], ai);
            af = fmaf(hk, wf[k], af);
            ag = fmaf(hk, wg[k], ag);
            ao = fmaf(hk, wo[k], ao);
        }
        float ig = fsig(ai), fg = fsig(af), og = fsig(ao);
        float gt = ftanh(ag);
        c = fg * c + ig * gt;
        h = og * ftanh(c);
        w[((size_t)s * 64 + b) * 16 + t] = h;
        xv = nx;
    }
}

// ---------------------------------------------------------------------------
// Kernel 3 (merged): out[row][i] = sum_k w[row][k] * Mats[k][i] for A, B, C.
// Block = 256 threads x f4 = 1024 cols, 64 rows. w rows read from LDS as
// f4 broadcasts (4 ds_read_b128/row). Nontemporal streaming stores.
// Grid: [0,512) -> A (4 col tiles), [512,768) -> B (2), [768,1152) -> C (3).
// ---------------------------------------------------------------------------
__global__ __launch_bounds__(256) void wsum_all_kernel(
    const float* __restrict__ w,   // [8192][16]
    const float* __restrict__ As, const float* __restrict__ Bs,
    const float* __restrict__ Cs,
    float* __restrict__ outA, float* __restrict__ outB, float* __restrict__ outC)
{
    __shared__ f4 ws4[256];    // 64 rows x 4 f4
    const int tid = threadIdx.x;
    const int bid = blockIdx.x;

    const float* M; float* o; int C, local, colTiles;
    if (bid < 512)      { M = As; o = outA; C = 4096; local = bid;       colTiles = 4; }
    else if (bid < 768) { M = Bs; o = outB; C = 2048; local = bid - 512; colTiles = 2; }
    else                { M = Cs; o = outC; C = 3072; local = bid - 768; colTiles = 3; }

    const int colTile  = local % colTiles;
    const int rowStart = (local / colTiles) * 64;
    const int i4 = colTile * 1024 + tid * 4;

    // stage 64 rows of w (1024 contiguous floats = 256 f4)
    ws4[tid] = reinterpret_cast<const f4*>(w)[rowStart * 4 + tid];

    // this thread's 4-column slice of all 16 matrices
    f4 m[16];
#pragma unroll
    for (int k = 0; k < 16; ++k)
        m[k] = *reinterpret_cast<const f4*>(&M[(size_t)k * C + i4]);

    __syncthreads();

    float* op = o + (size_t)rowStart * C + i4;
    for (int r = 0; r < 64; ++r) {
        f4 w0 = ws4[r * 4 + 0];   // ds_read_b128 broadcast
        f4 w1 = ws4[r * 4 + 1];
        f4 w2 = ws4[r * 4 + 2];
        f4 w3 = ws4[r * 4 + 3];
        f4 acc = (f4)0.f;
#pragma unroll
        for (int c4 = 0; c4 < 4; ++c4) acc += w0[c4] * m[c4 + 0];
#pragma unroll
        for (int c4 = 0; c4 < 4; ++c4) acc += w1[c4] * m[c4 + 4];
#pragma unroll
        for (int c4 = 0; c4 < 4; ++c4) acc += w2[c4] * m[c4 + 8];
#pragma unroll
        for (int c4 = 0; c4 < 4; ++c4) acc += w3[c4] * m[c4 + 12];
        __builtin_nontemporal_store(acc, reinterpret_cast<f4*>(op));
        op += C;
    }
}

// ---------------------------------------------------------------------------
extern "C" void kernel_launch(void* const* d_in, const int* in_sizes, int n_in,
                              void* d_out, int out_size, void* d_ws, size_t ws_size,
                              hipStream_t stream) {
    const float* state = (const float*)d_in[0];
    const float* W_ih  = (const float*)d_in[1];
    const float* W_hh  = (const float*)d_in[2];
    const float* b_ih  = (const float*)d_in[3];
    const float* b_hh  = (const float*)d_in[4];
    const float* As    = (const float*)d_in[5];
    const float* Bs    = (const float*)d_in[6];
    const float* Cs    = (const float*)d_in[7];
    float* out = (float*)d_out;

    float* xg = (float*)d_ws;            // 8192*64 floats
    float* w  = xg + (size_t)SB * 64;    // 8192*16 floats

    xgate_kernel<<<SB / 4, 256, 0, stream>>>(state, W_ih, b_ih, b_hh, xg);
    lstm_scan_kernel<<<16, 64, 0, stream>>>(xg, W_hh, w);

    float* outA = out;
    float* outB = out + (size_t)SB * 4096;
    float* outC = out + (size_t)SB * 4096 + (size_t)SB * 2048;

    wsum_all_kernel<<<1152, 256, 0, stream>>>(w, As, Bs, Cs, outA, outB, outC);
}

// Round 6
// 109.870 us; speedup vs baseline: 1.9994x; 1.1680x over previous
//
#include <hip/hip_runtime.h>
#include <hip/hip_bf16.h>

// Sizes: S=128, B=64, N=64, K=16, P=48, M=32
// Outputs: A [S,B,64,64] (C=4096), Bo [S,B,64,32] (C=2048), Cc [S,B,48,64] (C=3072)
#define SB 8192   // S*B

typedef float f4 __attribute__((ext_vector_type(4)));  // clang-native vec4

__device__ __forceinline__ float fsig(float x) {
    return __builtin_amdgcn_rcpf(1.f + __expf(-x));
}
__device__ __forceinline__ float ftanh(float x) {
    // tanh(x) = 1 - 2/(exp(2x)+1); correct limits at +-inf via rcp(inf)=0
    return fmaf(-2.f, __builtin_amdgcn_rcpf(1.f + __expf(2.f * x)), 1.f);
}

// ---------------------------------------------------------------------------
// Kernel 1: xg[row][t*4+q] = dot(x[row], W_ih[q*16+t]) + b_ih[g] + b_hh[g]
// Gate-interleaved layout so the scan loads one float4 per step.
// ---------------------------------------------------------------------------
__global__ __launch_bounds__(256) void xgate_kernel(
    const float* __restrict__ x,    // [8192][64]
    const float* __restrict__ Wih,  // [64][64]
    const float* __restrict__ bih,  // [64]
    const float* __restrict__ bhh,  // [64]
    float* __restrict__ xg)         // [8192][16][4] gate-interleaved
{
    __shared__ float xs[4][64];
    const int tid = threadIdx.x;
    const int rl  = tid >> 6;
    const int g   = tid & 63;           // weight row: g = q*16 + t
    const size_t rowBase = (size_t)blockIdx.x * 4;

    xs[rl][g] = x[rowBase * 64 + tid];
    __syncthreads();

    const float* xr = xs[rl];
    float acc = bih[g] + bhh[g];
#pragma unroll
    for (int n = 0; n < 64; n += 4) {
        f4 wv = *reinterpret_cast<const f4*>(&Wih[g * 64 + n]);
        acc = fmaf(xr[n + 0], wv.x, acc);
        acc = fmaf(xr[n + 1], wv.y, acc);
        acc = fmaf(xr[n + 2], wv.z, acc);
        acc = fmaf(xr[n + 3], wv.w, acc);
    }
    // remap: unit t = g&15, gate q = g>>4  ->  slot t*4+q
    xg[(rowBase + rl) * 64 + (g & 15) * 4 + (g >> 4)] = acc;
}

// ---------------------------------------------------------------------------
// Kernel 2: sequential LSTM scan. 16 blocks x 1 wave; thread owns (b, t).
// h broadcast via LDS write + f4 broadcast reads (fewer LDS ops than 16
// bpermutes). One float4 gate load per step, prefetched one step ahead.
// ---------------------------------------------------------------------------
__global__ __launch_bounds__(64) void lstm_scan_kernel(
    const float* __restrict__ xg,   // [S][B][16][4]
    const float* __restrict__ Whh,  // [64][16]
    float* __restrict__ w)          // [S][B][16]
{
    __shared__ alignas(16) float hs[64];
    const int tid = threadIdx.x;
    const int t  = tid & 15;        // hidden unit
    const int b4 = tid >> 4;        // local batch (0..3)
    const int b  = blockIdx.x * 4 + b4;

    float wi[16], wf[16], wg[16], wo[16];
#pragma unroll
    for (int k = 0; k < 16; ++k) {
        wi[k] = Whh[(0 * 16 + t) * 16 + k];
        wf[k] = Whh[(1 * 16 + t) * 16 + k];
        wg[k] = Whh[(2 * 16 + t) * 16 + k];
        wo[k] = Whh[(3 * 16 + t) * 16 + k];
    }

    // f4 view: element (s,b,t) at f4-index (s*64+b)*16 + t; s-stride = 1024
    const f4* xp = reinterpret_cast<const f4*>(xg) + b * 16 + t;
    f4 xv = xp[0];
    float h = 0.f, c = 0.f;
    for (int s = 0; s < 128; ++s) {
        f4 nx = (s < 127) ? xp[(size_t)(s + 1) * 1024] : (f4)0.f;

        hs[tid] = h;                 // publish h[b][t]
        __syncthreads();             // 1 wave: just lgkmcnt drain + barrier
        union { f4 v[4]; float f[16]; } hh;
        hh.v[0] = *reinterpret_cast<const f4*>(&hs[b4 * 16 + 0]);
        hh.v[1] = *reinterpret_cast<const f4*>(&hs[b4 * 16 + 4]);
        hh.v[2] = *reinterpret_cast<const f4*>(&hs[b4 * 16 + 8]);
        hh.v[3] = *reinterpret_cast<const f4*>(&hs[b4 * 16 + 12]);

        float ai = xv.x, af = xv.y, ag = xv.z, ao = xv.w;
#pragma unroll
        for (int k = 0; k < 16; ++k) {
            float hk = hh.f[k];
            ai = fmaf(hk, wi[k], ai);
            af = fmaf(hk, wf[k], af);
            ag = fmaf(hk, wg[k], ag);
            ao = fmaf(hk, wo[k], ao);
        }
        float ig = fsig(ai), fg = fsig(af), og = fsig(ao);
        float gt = ftanh(ag);
        c = fg * c + ig * gt;
        h = og * ftanh(c);
        w[((size_t)s * 64 + b) * 16 + t] = h;
        xv = nx;
    }
}

// ---------------------------------------------------------------------------
// Kernel 3 (merged): out[row][i] = sum_k w[row][k] * Mats[k][i] for A, B, C.
// Block = 256 threads x f4 = 1024 cols, 32 rows. 2304 blocks = 9/CU exactly.
// w rows are wave-uniform -> scalar s_load path (no LDS, no syncthreads).
// Matrix slice (16 f4 = 64 VGPR) in registers. Plain streaming f4 stores.
// Grid: [0,1024) -> A (4 col tiles), [1024,1536) -> B (2), rest -> C (3).
// ---------------------------------------------------------------------------
__global__ __launch_bounds__(256) void wsum_all_kernel(
    const float* __restrict__ w,   // [8192][16]
    const float* __restrict__ As, const float* __restrict__ Bs,
    const float* __restrict__ Cs,
    float* __restrict__ outA, float* __restrict__ outB, float* __restrict__ outC)
{
    const int tid = threadIdx.x;
    const int bid = blockIdx.x;

    const float* M; float* o; int C, local, colTiles;
    if (bid < 1024)      { M = As; o = outA; C = 4096; local = bid;        colTiles = 4; }
    else if (bid < 1536) { M = Bs; o = outB; C = 2048; local = bid - 1024; colTiles = 2; }
    else                 { M = Cs; o = outC; C = 3072; local = bid - 1536; colTiles = 3; }

    const int colTile  = local % colTiles;
    const int rowStart = (local / colTiles) * 32;
    const int i4 = colTile * 1024 + tid * 4;

    // this thread's 4-column slice of all 16 matrices
    f4 m[16];
#pragma unroll
    for (int k = 0; k < 16; ++k)
        m[k] = *reinterpret_cast<const f4*>(&M[(size_t)k * C + i4]);

    const float* wp = w + (size_t)rowStart * 16;   // wave-uniform
    float* op = o + (size_t)rowStart * C + i4;

#pragma unroll 2
    for (int r = 0; r < 32; ++r) {
        f4 acc = (f4)0.f;
#pragma unroll
        for (int k = 0; k < 16; ++k)
            acc += wp[r * 16 + k] * m[k];          // wp[..] uniform -> s_load
        *reinterpret_cast<f4*>(op) = acc;
        op += C;
    }
}

// ---------------------------------------------------------------------------
extern "C" void kernel_launch(void* const* d_in, const int* in_sizes, int n_in,
                              void* d_out, int out_size, void* d_ws, size_t ws_size,
                              hipStream_t stream) {
    const float* state = (const float*)d_in[0];
    const float* W_ih  = (const float*)d_in[1];
    const float* W_hh  = (const float*)d_in[2];
    const float* b_ih  = (const float*)d_in[3];
    const float* b_hh  = (const float*)d_in[4];
    const float* As    = (const float*)d_in[5];
    const float* Bs    = (const float*)d_in[6];
    const float* Cs    = (const float*)d_in[7];
    float* out = (float*)d_out;

    float* xg = (float*)d_ws;            // 8192*64 floats
    float* w  = xg + (size_t)SB * 64;    // 8192*16 floats

    xgate_kernel<<<SB / 4, 256, 0, stream>>>(state, W_ih, b_ih, b_hh, xg);
    lstm_scan_kernel<<<16, 64, 0, stream>>>(xg, W_hh, w);

    float* outA = out;
    float* outB = out + (size_t)SB * 4096;
    float* outC = out + (size_t)SB * 4096 + (size_t)SB * 2048;

    wsum_all_kernel<<<2304, 256, 0, stream>>>(w, As, Bs, Cs, outA, outB, outC);
}